// Round 1
// baseline (1344.038 us; speedup 1.0000x reference)
//
#include <hip/hip_runtime.h>
#include <hip/hip_bf16.h>

// GatedGCN layer: N=50000 nodes, E=500000 edges, D=128.
// Pipeline:
//   1. node_gemm: Ah,Bh,Dh,Eh = h @ W^T + b  (bf16 MFMA, W staged in LDS)
//   2. CSR build: hist -> scan -> scatter (edges sorted by dst)
//   3. edge_gemm: e_new = e@Wc^T + bc + Dh[src] + Eh[dst]  -> d_out e-region
//      (+ BN column sum/sumsq for e, register-accumulated, atomics once/wave)
//   4. aggregate: per-node gather of sigmoid(e_new)*Bh[src] via CSR -> h_new
//      (one wave per node, float2 lanes, data-prefetched)
//   5. hstats + finalize (fold BN into mul/add per column)
//   6. in-place epilogues: out = orig + relu(x*mul+add)
//
// R1 change: weights moved from 128 VGPRs to 32KB LDS (XOR-swizzled,
// conflict-free ds_read_b128) -> __launch_bounds__(256,4) for 16 waves/CU;
// bias folded into MFMA C-init; grids raised to 4 blocks/CU; aggregate
// rewritten wave-per-node with float2 + data prefetch.

#define NN 50000
#define NE 500000
#define DD 128

typedef __attribute__((ext_vector_type(8))) short short8;   // 8 x bf16
typedef __attribute__((ext_vector_type(4))) float floatx4;  // MFMA acc

__device__ inline short f2bf(float f) {
    unsigned u = __builtin_bit_cast(unsigned, f);
    u += 0x7FFFu + ((u >> 16) & 1u);   // round-to-nearest-even
    return (short)(u >> 16);
}

__device__ inline short8 load_frag(const float* __restrict__ p) {
    // 8 consecutive floats -> bf16x8 fragment (p is 32B aligned)
    float4 a = *(const float4*)p;
    float4 b = *(const float4*)(p + 4);
    short8 r;
    r[0] = f2bf(a.x); r[1] = f2bf(a.y); r[2] = f2bf(a.z); r[3] = f2bf(a.w);
    r[4] = f2bf(b.x); r[5] = f2bf(b.y); r[6] = f2bf(b.z); r[7] = f2bf(b.w);
    return r;
}

// Stage W (128x128 f32) into LDS as bf16, swizzled.
// Slot (row r, sub s) holds cols s*8..s*8+7 of row r at slot index
//   r*16 + (s ^ (r&15))   (16B per slot).
// Fragment read for (tn,c) by lane (m,quad): row=tn*16+m, sub=c*4+quad
//   -> byte addr = tn*4096 + m*256 + ((c*4+quad)^m)*16.
// Bank check: m*256 contributes 0 mod 32 banks; xor term spreads the 64
// lanes uniformly 8-per-bank-group -> conflict-free-optimal b128.
__device__ inline void stage_W(const float* __restrict__ W, short* Wlds) {
    int t = threadIdx.x;       // 0..255
    int r = t >> 1;            // row 0..127
    int half = t & 1;
#pragma unroll
    for (int k = 0; k < 8; k++) {
        int sub = half * 8 + k;
        const float* p = W + (size_t)r * DD + sub * 8;
        float4 a = *(const float4*)p;
        float4 b = *(const float4*)(p + 4);
        short8 v;
        v[0] = f2bf(a.x); v[1] = f2bf(a.y); v[2] = f2bf(a.z); v[3] = f2bf(a.w);
        v[4] = f2bf(b.x); v[5] = f2bf(b.y); v[6] = f2bf(b.z); v[7] = f2bf(b.w);
        int slot = r * 16 + (sub ^ (r & 15));
        *(short8*)&Wlds[slot * 8] = v;
    }
}

// ---------------- node GEMM: out = h @ W^T + b, one matrix per blockIdx.y ---
__launch_bounds__(256, 4)
__global__ void node_gemm(const float* __restrict__ h,
                          const float* W0, const float* W1, const float* W2, const float* W3,
                          const float* b0, const float* b1, const float* b2, const float* b3,
                          float* o0, float* o1, float* o2, float* o3) {
    __shared__ short Wlds[DD * DD];   // 32 KB
    int mtx = blockIdx.y;
    const float* W = (mtx == 0) ? W0 : (mtx == 1) ? W1 : (mtx == 2) ? W2 : W3;
    const float* bias_p = (mtx == 0) ? b0 : (mtx == 1) ? b1 : (mtx == 2) ? b2 : b3;
    float* out = (mtx == 0) ? o0 : (mtx == 1) ? o1 : (mtx == 2) ? o2 : o3;

    stage_W(W, Wlds);

    int lane = threadIdx.x & 63;
    int wid = threadIdx.x >> 6;
    int m = lane & 15, quad = lane >> 4;
    int gw = blockIdx.x * 4 + wid;
    int nw = gridDim.x * 4;

    float bias[8];
#pragma unroll
    for (int tn = 0; tn < 8; tn++) bias[tn] = bias_p[tn * 16 + m];

    int wbase[4];
#pragma unroll
    for (int c = 0; c < 4; c++)
        wbase[c] = (m * 16 + ((c * 4 + quad) ^ m)) * 16;

    __syncthreads();

    const int NT = NN / 16;  // 3125 row-tiles
    for (int t = gw; t < NT; t += nw) {
        int rowb = t * 16;
        short8 af[4];
#pragma unroll
        for (int c = 0; c < 4; c++)
            af[c] = load_frag(h + (size_t)(rowb + m) * DD + c * 32 + quad * 8);
        floatx4 acc[8];
#pragma unroll
        for (int tn = 0; tn < 8; tn++) acc[tn] = (floatx4)bias[tn];  // bias folded into C
#pragma unroll
        for (int tn = 0; tn < 8; tn++) {
#pragma unroll
            for (int c = 0; c < 4; c++) {
                short8 wfr = *(const short8*)((const char*)Wlds + (wbase[c] + tn * 4096));
                acc[tn] = __builtin_amdgcn_mfma_f32_16x16x32_bf16(af[c], wfr, acc[tn], 0, 0, 0);
            }
        }
        int r0 = rowb + quad * 4;
#pragma unroll
        for (int r = 0; r < 4; r++) {
            float* op = out + (size_t)(r0 + r) * DD;
#pragma unroll
            for (int tn = 0; tn < 8; tn++) {
                int col = tn * 16 + m;
                op[col] = acc[tn][r];
            }
        }
    }
}

// ---------------- edge GEMM fused: e_new = e@Wc^T + bc + Dh[src] + Eh[dst] --
__launch_bounds__(256, 4)
__global__ void edge_gemm(const float* __restrict__ e,
                          const float* __restrict__ Wc, const float* __restrict__ bc,
                          const float* __restrict__ Dh, const float* __restrict__ Eh,
                          const int* __restrict__ src, const int* __restrict__ dst,
                          float* __restrict__ enew,
                          float* __restrict__ cs_e, float* __restrict__ cq_e) {
    __shared__ short Wlds[DD * DD];   // 32 KB
    stage_W(Wc, Wlds);

    int lane = threadIdx.x & 63;
    int wid = threadIdx.x >> 6;
    int m = lane & 15, quad = lane >> 4;
    int gw = blockIdx.x * 4 + wid;
    int nw = gridDim.x * 4;

    float bias[8];
#pragma unroll
    for (int tn = 0; tn < 8; tn++) bias[tn] = bc[tn * 16 + m];

    int wbase[4];
#pragma unroll
    for (int c = 0; c < 4; c++)
        wbase[c] = (m * 16 + ((c * 4 + quad) ^ m)) * 16;

    __syncthreads();

    float ssum[8] = {};
    float ssq[8] = {};

    const int NT = NE / 16;  // 31250 row-tiles
    for (int t = gw; t < NT; t += nw) {
        int rowb = t * 16;
        short8 af[4];
#pragma unroll
        for (int c = 0; c < 4; c++)
            af[c] = load_frag(e + (size_t)(rowb + m) * DD + c * 32 + quad * 8);
        floatx4 acc[8];
#pragma unroll
        for (int tn = 0; tn < 8; tn++) acc[tn] = (floatx4)bias[tn];  // bias folded into C
#pragma unroll
        for (int tn = 0; tn < 8; tn++) {
#pragma unroll
            for (int c = 0; c < 4; c++) {
                short8 wfr = *(const short8*)((const char*)Wlds + (wbase[c] + tn * 4096));
                acc[tn] = __builtin_amdgcn_mfma_f32_16x16x32_bf16(af[c], wfr, acc[tn], 0, 0, 0);
            }
        }

        int e0 = rowb + quad * 4;
        int4 s4 = *(const int4*)(src + e0);
        int4 d4 = *(const int4*)(dst + e0);
        int sarr[4] = {s4.x, s4.y, s4.z, s4.w};
        int darr[4] = {d4.x, d4.y, d4.z, d4.w};
#pragma unroll
        for (int r = 0; r < 4; r++) {
            const float* dp = Dh + (size_t)sarr[r] * DD;
            const float* ep = Eh + (size_t)darr[r] * DD;
            float* op = enew + (size_t)(e0 + r) * DD;
#pragma unroll
            for (int tn = 0; tn < 8; tn++) {
                int col = tn * 16 + m;
                float v = acc[tn][r] + dp[col] + ep[col];
                op[col] = v;
                ssum[tn] += v;
                ssq[tn] += v * v;
            }
        }
    }

    // reduce BN partials across quads (lanes l, l^16, l^32, l^48 share a column)
#pragma unroll
    for (int tn = 0; tn < 8; tn++) {
        float s = ssum[tn], q = ssq[tn];
        s += __shfl_xor(s, 32); s += __shfl_xor(s, 16);
        q += __shfl_xor(q, 32); q += __shfl_xor(q, 16);
        if (quad == 0) {
            atomicAdd(&cs_e[tn * 16 + m], s);
            atomicAdd(&cq_e[tn * 16 + m], q);
        }
    }
}

// ---------------- CSR build ------------------------------------------------
__global__ void hist_kernel(const int* __restrict__ dst, int* __restrict__ counts) {
    int i = blockIdx.x * blockDim.x + threadIdx.x;
    if (i < NE) atomicAdd(&counts[dst[i]], 1);
}

__global__ void scan_kernel(const int* __restrict__ counts,
                            int* __restrict__ rowptr, int* __restrict__ cursor) {
    __shared__ int lds[1024];
    int t = threadIdx.x;
    const int CH = (NN + 1023) / 1024;  // 49
    int begin = t * CH;
    int end = begin + CH; if (end > NN) end = NN; if (begin > NN) begin = NN;
    int s = 0;
    for (int i = begin; i < end; i++) s += counts[i];
    lds[t] = s;
    __syncthreads();
    for (int off = 1; off < 1024; off <<= 1) {
        int v = lds[t];
        int add = (t >= off) ? lds[t - off] : 0;
        __syncthreads();
        lds[t] = v + add;
        __syncthreads();
    }
    int run = (t == 0) ? 0 : lds[t - 1];
    for (int i = begin; i < end; i++) {
        rowptr[i] = run; cursor[i] = run;
        run += counts[i];
    }
    if (t == 1023) rowptr[NN] = run;  // == NE
}

__global__ void scatter_kernel(const int* __restrict__ src, const int* __restrict__ dst,
                               int* __restrict__ cursor,
                               int* __restrict__ eidx, int* __restrict__ ssrc) {
    int i = blockIdx.x * blockDim.x + threadIdx.x;
    if (i < NE) {
        int d = dst[i];
        int pos = atomicAdd(&cursor[d], 1);
        eidx[pos] = i;
        ssrc[pos] = src[i];
    }
}

// ---------------- gated aggregation (CSR, no float atomics) ----------------
// One wave per node; lane l owns columns 2l, 2l+1 (float2 = full 512B row
// per instruction); 1-deep data prefetch to hide gather latency.
__launch_bounds__(256)
__global__ void aggregate(const int* __restrict__ rowptr, const int* __restrict__ eidx,
                          const int* __restrict__ ssrc,
                          const float* __restrict__ enew, const float* __restrict__ Bh,
                          const float* __restrict__ Ah, float* __restrict__ hnew) {
    int gw = (blockIdx.x * blockDim.x + threadIdx.x) >> 6;  // global wave = node
    int lane = threadIdx.x & 63;
    if (gw >= NN) return;
    int s = rowptr[gw], e = rowptr[gw + 1];
    int c0 = lane * 2;
    float a1x = 0.f, a1y = 0.f, a2x = 0.f, a2y = 0.f;
    float2 xv = {0.f, 0.f}, bv = {0.f, 0.f};
    if (s < e) {
        int eid = eidx[s], sr = ssrc[s];
        xv = *(const float2*)(enew + (size_t)eid * DD + c0);
        bv = *(const float2*)(Bh + (size_t)sr * DD + c0);
    }
    for (int j = s; j < e; j++) {
        float2 x = xv, b = bv;
        if (j + 1 < e) {
            int eid2 = eidx[j + 1], sr2 = ssrc[j + 1];
            xv = *(const float2*)(enew + (size_t)eid2 * DD + c0);
            bv = *(const float2*)(Bh + (size_t)sr2 * DD + c0);
        }
        float sx = 1.f / (1.f + __expf(-x.x));
        float sy = 1.f / (1.f + __expf(-x.y));
        a1x = fmaf(sx, b.x, a1x); a1y = fmaf(sy, b.y, a1y);
        a2x += sx; a2y += sy;
    }
    float2 ah = *(const float2*)(Ah + (size_t)gw * DD + c0);
    float2 o;
    o.x = ah.x + a1x / (a2x + 1e-6f);
    o.y = ah.y + a1y / (a2y + 1e-6f);
    *(float2*)(hnew + (size_t)gw * DD + c0) = o;
}

// ---------------- BN stats for h -------------------------------------------
__global__ void hstats(const float* __restrict__ hnew, float* __restrict__ cs, float* __restrict__ cq) {
    int d = threadIdx.x;  // 128
    float s = 0.f, q = 0.f;
    for (int v = blockIdx.x; v < NN; v += gridDim.x) {
        float x = hnew[(size_t)v * DD + d];
        s += x; q += x * x;
    }
    atomicAdd(&cs[d], s);
    atomicAdd(&cq[d], q);
}

// ---------------- fold BN into per-column mul/add --------------------------
__global__ void finalize(const float* cs_e, const float* cq_e,
                         const float* cs_h, const float* cq_h,
                         const float* ge, const float* be,
                         const float* gh, const float* bh,
                         float* mul_e, float* add_e, float* mul_h, float* add_h) {
    int d = threadIdx.x;
    float me = cs_e[d] / (float)NE;
    float ve = cq_e[d] / (float)NE - me * me;
    float se = rsqrtf(ve + 1e-5f) * ge[d];
    mul_e[d] = se; add_e[d] = be[d] - me * se;
    float mh = cs_h[d] / (float)NN;
    float vh = cq_h[d] / (float)NN - mh * mh;
    float sh = rsqrtf(vh + 1e-5f) * gh[d];
    mul_h[d] = sh; add_h[d] = bh[d] - mh * sh;
}

// ---------------- in-place epilogue: x = orig + relu(x*mul+add) ------------
__global__ void out_transform(float* __restrict__ x, const float* __restrict__ orig,
                              const float* __restrict__ mul, const float* __restrict__ add,
                              int total4) {
    int i = blockIdx.x * blockDim.x + threadIdx.x;
    if (i >= total4) return;
    float4 xv = ((const float4*)x)[i];
    float4 ov = ((const float4*)orig)[i];
    int col = (i * 4) & (DD - 1);
    float4 mu = *(const float4*)(mul + col);
    float4 ad = *(const float4*)(add + col);
    float4 y;
    y.x = fmaxf(fmaf(xv.x, mu.x, ad.x), 0.f) + ov.x;
    y.y = fmaxf(fmaf(xv.y, mu.y, ad.y), 0.f) + ov.y;
    y.z = fmaxf(fmaf(xv.z, mu.z, ad.z), 0.f) + ov.z;
    y.w = fmaxf(fmaf(xv.w, mu.w, ad.w), 0.f) + ov.w;
    ((float4*)x)[i] = y;
}

extern "C" void kernel_launch(void* const* d_in, const int* in_sizes, int n_in,
                              void* d_out, int out_size, void* d_ws, size_t ws_size,
                              hipStream_t stream) {
    const float* h   = (const float*)d_in[0];
    const float* e   = (const float*)d_in[1];
    const int*   src = (const int*)d_in[2];
    const int*   dst = (const int*)d_in[3];
    const float* W_A = (const float*)d_in[4];  const float* b_A = (const float*)d_in[5];
    const float* W_B = (const float*)d_in[6];  const float* b_B = (const float*)d_in[7];
    const float* W_C = (const float*)d_in[8];  const float* b_C = (const float*)d_in[9];
    const float* W_D = (const float*)d_in[10]; const float* b_D = (const float*)d_in[11];
    const float* W_E = (const float*)d_in[12]; const float* b_E = (const float*)d_in[13];
    const float* gamma_h = (const float*)d_in[14]; const float* beta_h = (const float*)d_in[15];
    const float* gamma_e = (const float*)d_in[16]; const float* beta_e = (const float*)d_in[17];

    float* out_h = (float*)d_out;              // h_new then h_out in place
    float* out_e = out_h + (size_t)NN * DD;    // e_new then e_out in place

    char* ws = (char*)d_ws;
    float* Ah = (float*)(ws + 0);
    float* Bh = (float*)(ws + 25600000);
    float* Dh = (float*)(ws + 51200000);
    float* Eh = (float*)(ws + 76800000);
    int* rowptr = (int*)(ws + 102400000);      // NN+1 ints
    int* counts = (int*)(ws + 102600192);      // NN ints
    int* cursor = (int*)(ws + 102800192);      // NN ints
    int* eidx   = (int*)(ws + 103000192);      // NE ints
    int* ssrc   = (int*)(ws + 105000192);      // NE ints
    float* stats = (float*)(ws + 107000192);   // 8 x 128 floats
    float* cs_e = stats + 0 * DD;
    float* cq_e = stats + 1 * DD;
    float* cs_h = stats + 2 * DD;
    float* cq_h = stats + 3 * DD;
    float* mul_e = stats + 4 * DD;
    float* add_e = stats + 5 * DD;
    float* mul_h = stats + 6 * DD;
    float* add_h = stats + 7 * DD;

    hipMemsetAsync(counts, 0, NN * sizeof(int), stream);
    hipMemsetAsync(stats, 0, 4 * DD * sizeof(float), stream);

    node_gemm<<<dim3(256, 4), 256, 0, stream>>>(h, W_A, W_B, W_D, W_E,
                                                b_A, b_B, b_D, b_E,
                                                Ah, Bh, Dh, Eh);

    int nb_edge = (NE + 255) / 256;
    hist_kernel<<<nb_edge, 256, 0, stream>>>(dst, counts);
    scan_kernel<<<1, 1024, 0, stream>>>(counts, rowptr, cursor);
    scatter_kernel<<<nb_edge, 256, 0, stream>>>(src, dst, cursor, eidx, ssrc);

    edge_gemm<<<1024, 256, 0, stream>>>(e, W_C, b_C, Dh, Eh, src, dst,
                                        out_e, cs_e, cq_e);

    aggregate<<<(NN * 64 + 255) / 256, 256, 0, stream>>>(rowptr, eidx, ssrc, out_e, Bh, Ah, out_h);

    hstats<<<256, DD, 0, stream>>>(out_h, cs_h, cq_h);

    finalize<<<1, DD, 0, stream>>>(cs_e, cq_e, cs_h, cq_h,
                                   gamma_e, beta_e, gamma_h, beta_h,
                                   mul_e, add_e, mul_h, add_h);

    out_transform<<<(NN * DD / 4 + 255) / 256, 256, 0, stream>>>(out_h, h, mul_h, add_h, NN * DD / 4);
    out_transform<<<(NE * DD / 4 + 255) / 256, 256, 0, stream>>>(out_e, e, mul_e, add_e, NE * DD / 4);
}

// Round 3
// 1133.951 us; speedup vs baseline: 1.1853x; 1.1853x over previous
//
#include <hip/hip_runtime.h>
#include <hip/hip_bf16.h>

// GatedGCN layer: N=50000 nodes, E=500000 edges, D=128.
// Pipeline:
//   1. node_gemm: Ah,Bh,Dh,Eh = h @ W^T + b  (bf16 MFMA, W staged in LDS)
//   2. CSR build: hist -> scan -> scatter (edges sorted by dst)
//   3. edge_gemm: e_new = e@Wc^T + bc + Dh[src] + Eh[dst]  -> d_out e-region
//      (+ BN column sum/sumsq for e, register-accumulated, atomics once/wave)
//   4. aggregate: per-node gather of sigmoid(e_new)*Bh[src] via CSR -> h_new
//      (one wave per node, float2 lanes, data-prefetched)
//   5. hstats + finalize (fold BN into mul/add per column)
//   6. in-place epilogues: out = orig + relu(x*mul+add)
//
// R3 = R2 resubmitted (R2 bench was an infra failure, container died twice;
// no kernel-side error). Change vs R1: launch_bounds(256,2) (VGPR budget 256
// -> no spill of BN accumulators) + edge grid 768 (3 blk/CU, 12 waves/CU)
// -- keeps 3.4x R0's latency hiding without R1's L2 gather thrash.

#define NN 50000
#define NE 500000
#define DD 128

typedef __attribute__((ext_vector_type(8))) short short8;   // 8 x bf16
typedef __attribute__((ext_vector_type(4))) float floatx4;  // MFMA acc

__device__ inline short f2bf(float f) {
    unsigned u = __builtin_bit_cast(unsigned, f);
    u += 0x7FFFu + ((u >> 16) & 1u);   // round-to-nearest-even
    return (short)(u >> 16);
}

__device__ inline short8 load_frag(const float* __restrict__ p) {
    // 8 consecutive floats -> bf16x8 fragment (p is 32B aligned)
    float4 a = *(const float4*)p;
    float4 b = *(const float4*)(p + 4);
    short8 r;
    r[0] = f2bf(a.x); r[1] = f2bf(a.y); r[2] = f2bf(a.z); r[3] = f2bf(a.w);
    r[4] = f2bf(b.x); r[5] = f2bf(b.y); r[6] = f2bf(b.z); r[7] = f2bf(b.w);
    return r;
}

// Stage W (128x128 f32) into LDS as bf16, swizzled.
// Slot (row r, sub s) holds cols s*8..s*8+7 of row r at slot index
//   r*16 + (s ^ (r&15))   (16B per slot).
// Fragment read for (tn,c) by lane (m,quad): row=tn*16+m, sub=c*4+quad
//   -> byte addr = tn*4096 + m*256 + ((c*4+quad)^m)*16.
// Bank check: m*256 contributes 0 mod 32 banks; xor term spreads the 64
// lanes uniformly 8-per-bank-group -> conflict-free-optimal b128.
__device__ inline void stage_W(const float* __restrict__ W, short* Wlds) {
    int t = threadIdx.x;       // 0..255
    int r = t >> 1;            // row 0..127
    int half = t & 1;
#pragma unroll
    for (int k = 0; k < 8; k++) {
        int sub = half * 8 + k;
        const float* p = W + (size_t)r * DD + sub * 8;
        float4 a = *(const float4*)p;
        float4 b = *(const float4*)(p + 4);
        short8 v;
        v[0] = f2bf(a.x); v[1] = f2bf(a.y); v[2] = f2bf(a.z); v[3] = f2bf(a.w);
        v[4] = f2bf(b.x); v[5] = f2bf(b.y); v[6] = f2bf(b.z); v[7] = f2bf(b.w);
        int slot = r * 16 + (sub ^ (r & 15));
        *(short8*)&Wlds[slot * 8] = v;
    }
}

// ---------------- node GEMM: out = h @ W^T + b, one matrix per blockIdx.y ---
__launch_bounds__(256, 2)
__global__ void node_gemm(const float* __restrict__ h,
                          const float* W0, const float* W1, const float* W2, const float* W3,
                          const float* b0, const float* b1, const float* b2, const float* b3,
                          float* o0, float* o1, float* o2, float* o3) {
    __shared__ short Wlds[DD * DD];   // 32 KB
    int mtx = blockIdx.y;
    const float* W = (mtx == 0) ? W0 : (mtx == 1) ? W1 : (mtx == 2) ? W2 : W3;
    const float* bias_p = (mtx == 0) ? b0 : (mtx == 1) ? b1 : (mtx == 2) ? b2 : b3;
    float* out = (mtx == 0) ? o0 : (mtx == 1) ? o1 : (mtx == 2) ? o2 : o3;

    stage_W(W, Wlds);

    int lane = threadIdx.x & 63;
    int wid = threadIdx.x >> 6;
    int m = lane & 15, quad = lane >> 4;
    int gw = blockIdx.x * 4 + wid;
    int nw = gridDim.x * 4;

    float bias[8];
#pragma unroll
    for (int tn = 0; tn < 8; tn++) bias[tn] = bias_p[tn * 16 + m];

    int wbase[4];
#pragma unroll
    for (int c = 0; c < 4; c++)
        wbase[c] = (m * 16 + ((c * 4 + quad) ^ m)) * 16;

    __syncthreads();

    const int NT = NN / 16;  // 3125 row-tiles
    for (int t = gw; t < NT; t += nw) {
        int rowb = t * 16;
        short8 af[4];
#pragma unroll
        for (int c = 0; c < 4; c++)
            af[c] = load_frag(h + (size_t)(rowb + m) * DD + c * 32 + quad * 8);
        floatx4 acc[8];
#pragma unroll
        for (int tn = 0; tn < 8; tn++) acc[tn] = (floatx4)bias[tn];  // bias folded into C
#pragma unroll
        for (int tn = 0; tn < 8; tn++) {
#pragma unroll
            for (int c = 0; c < 4; c++) {
                short8 wfr = *(const short8*)((const char*)Wlds + (wbase[c] + tn * 4096));
                acc[tn] = __builtin_amdgcn_mfma_f32_16x16x32_bf16(af[c], wfr, acc[tn], 0, 0, 0);
            }
        }
        int r0 = rowb + quad * 4;
#pragma unroll
        for (int r = 0; r < 4; r++) {
            float* op = out + (size_t)(r0 + r) * DD;
#pragma unroll
            for (int tn = 0; tn < 8; tn++) {
                int col = tn * 16 + m;
                op[col] = acc[tn][r];
            }
        }
    }
}

// ---------------- edge GEMM fused: e_new = e@Wc^T + bc + Dh[src] + Eh[dst] --
__launch_bounds__(256, 2)
__global__ void edge_gemm(const float* __restrict__ e,
                          const float* __restrict__ Wc, const float* __restrict__ bc,
                          const float* __restrict__ Dh, const float* __restrict__ Eh,
                          const int* __restrict__ src, const int* __restrict__ dst,
                          float* __restrict__ enew,
                          float* __restrict__ cs_e, float* __restrict__ cq_e) {
    __shared__ short Wlds[DD * DD];   // 32 KB
    stage_W(Wc, Wlds);

    int lane = threadIdx.x & 63;
    int wid = threadIdx.x >> 6;
    int m = lane & 15, quad = lane >> 4;
    int gw = blockIdx.x * 4 + wid;
    int nw = gridDim.x * 4;

    float bias[8];
#pragma unroll
    for (int tn = 0; tn < 8; tn++) bias[tn] = bc[tn * 16 + m];

    int wbase[4];
#pragma unroll
    for (int c = 0; c < 4; c++)
        wbase[c] = (m * 16 + ((c * 4 + quad) ^ m)) * 16;

    __syncthreads();

    float ssum[8] = {};
    float ssq[8] = {};

    const int NT = NE / 16;  // 31250 row-tiles
    for (int t = gw; t < NT; t += nw) {
        int rowb = t * 16;
        short8 af[4];
#pragma unroll
        for (int c = 0; c < 4; c++)
            af[c] = load_frag(e + (size_t)(rowb + m) * DD + c * 32 + quad * 8);
        floatx4 acc[8];
#pragma unroll
        for (int tn = 0; tn < 8; tn++) acc[tn] = (floatx4)bias[tn];  // bias folded into C
#pragma unroll
        for (int tn = 0; tn < 8; tn++) {
#pragma unroll
            for (int c = 0; c < 4; c++) {
                short8 wfr = *(const short8*)((const char*)Wlds + (wbase[c] + tn * 4096));
                acc[tn] = __builtin_amdgcn_mfma_f32_16x16x32_bf16(af[c], wfr, acc[tn], 0, 0, 0);
            }
        }

        int e0 = rowb + quad * 4;
        int4 s4 = *(const int4*)(src + e0);
        int4 d4 = *(const int4*)(dst + e0);
        int sarr[4] = {s4.x, s4.y, s4.z, s4.w};
        int darr[4] = {d4.x, d4.y, d4.z, d4.w};
#pragma unroll
        for (int r = 0; r < 4; r++) {
            const float* dp = Dh + (size_t)sarr[r] * DD;
            const float* ep = Eh + (size_t)darr[r] * DD;
            float* op = enew + (size_t)(e0 + r) * DD;
#pragma unroll
            for (int tn = 0; tn < 8; tn++) {
                int col = tn * 16 + m;
                float v = acc[tn][r] + dp[col] + ep[col];
                op[col] = v;
                ssum[tn] += v;
                ssq[tn] += v * v;
            }
        }
    }

    // reduce BN partials across quads (lanes l, l^16, l^32, l^48 share a column)
#pragma unroll
    for (int tn = 0; tn < 8; tn++) {
        float s = ssum[tn], q = ssq[tn];
        s += __shfl_xor(s, 32); s += __shfl_xor(s, 16);
        q += __shfl_xor(q, 32); q += __shfl_xor(q, 16);
        if (quad == 0) {
            atomicAdd(&cs_e[tn * 16 + m], s);
            atomicAdd(&cq_e[tn * 16 + m], q);
        }
    }
}

// ---------------- CSR build ------------------------------------------------
__global__ void hist_kernel(const int* __restrict__ dst, int* __restrict__ counts) {
    int i = blockIdx.x * blockDim.x + threadIdx.x;
    if (i < NE) atomicAdd(&counts[dst[i]], 1);
}

__global__ void scan_kernel(const int* __restrict__ counts,
                            int* __restrict__ rowptr, int* __restrict__ cursor) {
    __shared__ int lds[1024];
    int t = threadIdx.x;
    const int CH = (NN + 1023) / 1024;  // 49
    int begin = t * CH;
    int end = begin + CH; if (end > NN) end = NN; if (begin > NN) begin = NN;
    int s = 0;
    for (int i = begin; i < end; i++) s += counts[i];
    lds[t] = s;
    __syncthreads();
    for (int off = 1; off < 1024; off <<= 1) {
        int v = lds[t];
        int add = (t >= off) ? lds[t - off] : 0;
        __syncthreads();
        lds[t] = v + add;
        __syncthreads();
    }
    int run = (t == 0) ? 0 : lds[t - 1];
    for (int i = begin; i < end; i++) {
        rowptr[i] = run; cursor[i] = run;
        run += counts[i];
    }
    if (t == 1023) rowptr[NN] = run;  // == NE
}

__global__ void scatter_kernel(const int* __restrict__ src, const int* __restrict__ dst,
                               int* __restrict__ cursor,
                               int* __restrict__ eidx, int* __restrict__ ssrc) {
    int i = blockIdx.x * blockDim.x + threadIdx.x;
    if (i < NE) {
        int d = dst[i];
        int pos = atomicAdd(&cursor[d], 1);
        eidx[pos] = i;
        ssrc[pos] = src[i];
    }
}

// ---------------- gated aggregation (CSR, no float atomics) ----------------
// One wave per node; lane l owns columns 2l, 2l+1 (float2 = full 512B row
// per instruction); 1-deep data prefetch to hide gather latency.
__launch_bounds__(256)
__global__ void aggregate(const int* __restrict__ rowptr, const int* __restrict__ eidx,
                          const int* __restrict__ ssrc,
                          const float* __restrict__ enew, const float* __restrict__ Bh,
                          const float* __restrict__ Ah, float* __restrict__ hnew) {
    int gw = (blockIdx.x * blockDim.x + threadIdx.x) >> 6;  // global wave = node
    int lane = threadIdx.x & 63;
    if (gw >= NN) return;
    int s = rowptr[gw], e = rowptr[gw + 1];
    int c0 = lane * 2;
    float a1x = 0.f, a1y = 0.f, a2x = 0.f, a2y = 0.f;
    float2 xv = {0.f, 0.f}, bv = {0.f, 0.f};
    if (s < e) {
        int eid = eidx[s], sr = ssrc[s];
        xv = *(const float2*)(enew + (size_t)eid * DD + c0);
        bv = *(const float2*)(Bh + (size_t)sr * DD + c0);
    }
    for (int j = s; j < e; j++) {
        float2 x = xv, b = bv;
        if (j + 1 < e) {
            int eid2 = eidx[j + 1], sr2 = ssrc[j + 1];
            xv = *(const float2*)(enew + (size_t)eid2 * DD + c0);
            bv = *(const float2*)(Bh + (size_t)sr2 * DD + c0);
        }
        float sx = 1.f / (1.f + __expf(-x.x));
        float sy = 1.f / (1.f + __expf(-x.y));
        a1x = fmaf(sx, b.x, a1x); a1y = fmaf(sy, b.y, a1y);
        a2x += sx; a2y += sy;
    }
    float2 ah = *(const float2*)(Ah + (size_t)gw * DD + c0);
    float2 o;
    o.x = ah.x + a1x / (a2x + 1e-6f);
    o.y = ah.y + a1y / (a2y + 1e-6f);
    *(float2*)(hnew + (size_t)gw * DD + c0) = o;
}

// ---------------- BN stats for h -------------------------------------------
__global__ void hstats(const float* __restrict__ hnew, float* __restrict__ cs, float* __restrict__ cq) {
    int d = threadIdx.x;  // 128
    float s = 0.f, q = 0.f;
    for (int v = blockIdx.x; v < NN; v += gridDim.x) {
        float x = hnew[(size_t)v * DD + d];
        s += x; q += x * x;
    }
    atomicAdd(&cs[d], s);
    atomicAdd(&cq[d], q);
}

// ---------------- fold BN into per-column mul/add --------------------------
__global__ void finalize(const float* cs_e, const float* cq_e,
                         const float* cs_h, const float* cq_h,
                         const float* ge, const float* be,
                         const float* gh, const float* bh,
                         float* mul_e, float* add_e, float* mul_h, float* add_h) {
    int d = threadIdx.x;
    float me = cs_e[d] / (float)NE;
    float ve = cq_e[d] / (float)NE - me * me;
    float se = rsqrtf(ve + 1e-5f) * ge[d];
    mul_e[d] = se; add_e[d] = be[d] - me * se;
    float mh = cs_h[d] / (float)NN;
    float vh = cq_h[d] / (float)NN - mh * mh;
    float sh = rsqrtf(vh + 1e-5f) * gh[d];
    mul_h[d] = sh; add_h[d] = bh[d] - mh * sh;
}

// ---------------- in-place epilogue: x = orig + relu(x*mul+add) ------------
__global__ void out_transform(float* __restrict__ x, const float* __restrict__ orig,
                              const float* __restrict__ mul, const float* __restrict__ add,
                              int total4) {
    int i = blockIdx.x * blockDim.x + threadIdx.x;
    if (i >= total4) return;
    float4 xv = ((const float4*)x)[i];
    float4 ov = ((const float4*)orig)[i];
    int col = (i * 4) & (DD - 1);
    float4 mu = *(const float4*)(mul + col);
    float4 ad = *(const float4*)(add + col);
    float4 y;
    y.x = fmaxf(fmaf(xv.x, mu.x, ad.x), 0.f) + ov.x;
    y.y = fmaxf(fmaf(xv.y, mu.y, ad.y), 0.f) + ov.y;
    y.z = fmaxf(fmaf(xv.z, mu.z, ad.z), 0.f) + ov.z;
    y.w = fmaxf(fmaf(xv.w, mu.w, ad.w), 0.f) + ov.w;
    ((float4*)x)[i] = y;
}

extern "C" void kernel_launch(void* const* d_in, const int* in_sizes, int n_in,
                              void* d_out, int out_size, void* d_ws, size_t ws_size,
                              hipStream_t stream) {
    const float* h   = (const float*)d_in[0];
    const float* e   = (const float*)d_in[1];
    const int*   src = (const int*)d_in[2];
    const int*   dst = (const int*)d_in[3];
    const float* W_A = (const float*)d_in[4];  const float* b_A = (const float*)d_in[5];
    const float* W_B = (const float*)d_in[6];  const float* b_B = (const float*)d_in[7];
    const float* W_C = (const float*)d_in[8];  const float* b_C = (const float*)d_in[9];
    const float* W_D = (const float*)d_in[10]; const float* b_D = (const float*)d_in[11];
    const float* W_E = (const float*)d_in[12]; const float* b_E = (const float*)d_in[13];
    const float* gamma_h = (const float*)d_in[14]; const float* beta_h = (const float*)d_in[15];
    const float* gamma_e = (const float*)d_in[16]; const float* beta_e = (const float*)d_in[17];

    float* out_h = (float*)d_out;              // h_new then h_out in place
    float* out_e = out_h + (size_t)NN * DD;    // e_new then e_out in place

    char* ws = (char*)d_ws;
    float* Ah = (float*)(ws + 0);
    float* Bh = (float*)(ws + 25600000);
    float* Dh = (float*)(ws + 51200000);
    float* Eh = (float*)(ws + 76800000);
    int* rowptr = (int*)(ws + 102400000);      // NN+1 ints
    int* counts = (int*)(ws + 102600192);      // NN ints
    int* cursor = (int*)(ws + 102800192);      // NN ints
    int* eidx   = (int*)(ws + 103000192);      // NE ints
    int* ssrc   = (int*)(ws + 105000192);      // NE ints
    float* stats = (float*)(ws + 107000192);   // 8 x 128 floats
    float* cs_e = stats + 0 * DD;
    float* cq_e = stats + 1 * DD;
    float* cs_h = stats + 2 * DD;
    float* cq_h = stats + 3 * DD;
    float* mul_e = stats + 4 * DD;
    float* add_e = stats + 5 * DD;
    float* mul_h = stats + 6 * DD;
    float* add_h = stats + 7 * DD;

    hipMemsetAsync(counts, 0, NN * sizeof(int), stream);
    hipMemsetAsync(stats, 0, 4 * DD * sizeof(float), stream);

    node_gemm<<<dim3(256, 4), 256, 0, stream>>>(h, W_A, W_B, W_D, W_E,
                                                b_A, b_B, b_D, b_E,
                                                Ah, Bh, Dh, Eh);

    int nb_edge = (NE + 255) / 256;
    hist_kernel<<<nb_edge, 256, 0, stream>>>(dst, counts);
    scan_kernel<<<1, 1024, 0, stream>>>(counts, rowptr, cursor);
    scatter_kernel<<<nb_edge, 256, 0, stream>>>(src, dst, cursor, eidx, ssrc);

    edge_gemm<<<768, 256, 0, stream>>>(e, W_C, b_C, Dh, Eh, src, dst,
                                       out_e, cs_e, cq_e);

    aggregate<<<(NN * 64 + 255) / 256, 256, 0, stream>>>(rowptr, eidx, ssrc, out_e, Bh, Ah, out_h);

    hstats<<<256, DD, 0, stream>>>(out_h, cs_h, cq_h);

    finalize<<<1, DD, 0, stream>>>(cs_e, cq_e, cs_h, cq_h,
                                   gamma_e, beta_e, gamma_h, beta_h,
                                   mul_e, add_e, mul_h, add_h);

    out_transform<<<(NN * DD / 4 + 255) / 256, 256, 0, stream>>>(out_h, h, mul_h, add_h, NN * DD / 4);
    out_transform<<<(NE * DD / 4 + 255) / 256, 256, 0, stream>>>(out_e, e, mul_e, add_e, NE * DD / 4);
}